// Round 6
// baseline (635.133 us; speedup 1.0000x reference)
//
#include <hip/hip_runtime.h>
#include <math.h>

constexpr int NN = 4000;
constexpr int EE = 48000;
constexpr int ZZ = 10;
constexpr float RMAX = 5.0f;
constexpr float INV_AVG = 1.0f / 12.0f;

constexpr int GRID  = 512;            // 2 blocks/CU x 256 CU -> all co-resident at <=256 VGPR
constexpr int NWAVE = GRID * 4;

// phase-1 role layout
constexpr int RB_SPEC = 188;          // [0,188)   edges (48128 threads)
constexpr int RB_W3Z  = 204;          // [188,204) species
constexpr int RB_T0   = 236;          // [204,236) Wm3 l=0 gather
constexpr int RB_ZERO = 239;          // [236,239) T0/SC0 tables; [239,512) zero role
constexpr int ZWS_F4  = 3*NN*64/4;    // agg0,agg1,ghb
constexpr int ZOUT_F4 = 3*NN/4;       // force region of out

__device__ __forceinline__ float rl(float v, int lane){
    return __uint_as_float(__builtin_amdgcn_readlane(__float_as_uint(v), lane));
}
__device__ __forceinline__ float sigf(float x){ return 1.0f/(1.0f+__expf(-x)); }
__device__ __forceinline__ float siluf(float x){ return x*sigf(x); }
__device__ __forceinline__ float dsiluf(float x){ float s=sigf(x); return s*(1.0f+x*(1.0f-s)); }

__device__ __forceinline__ void pin64(float (&W)[64]){
#pragma unroll
    for (int i=0;i<64;i++) asm volatile("" : "+v"(W[i]));
}
__device__ __forceinline__ void pin8(float (&W)[8]){
#pragma unroll
    for (int i=0;i<8;i++) asm volatile("" : "+v"(W[i]));
}
__device__ __forceinline__ float bmv64(float src, const float (&W)[64]){
    float a0=0.f,a1=0.f,a2=0.f,a3=0.f;
#pragma unroll
    for (int k=0;k<64;k+=4){
        a0 += rl(src,k+0)*W[k+0];
        a1 += rl(src,k+1)*W[k+1];
        a2 += rl(src,k+2)*W[k+2];
        a3 += rl(src,k+3)*W[k+3];
    }
    return (a0+a1)+(a2+a3);
}
__device__ __forceinline__ void load_row64(const float* __restrict__ p, float (&W)[64]){
#pragma unroll
    for (int i=0;i<16;i++){
        float4 v = reinterpret_cast<const float4*>(p)[i];
        W[4*i]=v.x; W[4*i+1]=v.y; W[4*i+2]=v.z; W[4*i+3]=v.w;
    }
}
__device__ __forceinline__ void load_col64(const float* __restrict__ p, int lane, float (&W)[64]){
#pragma unroll
    for (int k=0;k<64;k++) W[k] = p[k*64+lane];
}

// device-wide barrier: per-id dedicated counter (zeroed by k_zero each call)
__device__ __forceinline__ void gbar(int* __restrict__ bc, int id){
    __syncthreads();
    if (threadIdx.x == 0){
        __threadfence();   // release: flush this XCD's dirty L2 so other XCDs can see our writes
        __hip_atomic_fetch_add(bc + id*64, 1, __ATOMIC_RELEASE, __HIP_MEMORY_SCOPE_AGENT);
        while (__hip_atomic_load(bc + id*64, __ATOMIC_ACQUIRE, __HIP_MEMORY_SCOPE_AGENT) < GRID)
            __builtin_amdgcn_s_sleep(1);
        __threadfence();   // acquire: invalidate stale L1/L2 before reading others' writes
    }
    __syncthreads();
}

// ---------------- tiny pre-kernel: barrier counters + ecount + snap header ----------------
__global__ void k_zero(int* __restrict__ barcnt, int* __restrict__ ecount, float* __restrict__ out)
{
    int t = threadIdx.x;
    barcnt[t] = 0; barcnt[t+256] = 0;
    if (t == 0) *ecount = 0;
    if (t < 8) out[t] = 0.0f;
}

// ---------------- the whole model: 8 phases, 7 device barriers ----------------
__global__ __launch_bounds__(256,2)
void k_main(const float* __restrict__ pos, const float* __restrict__ shifts,
            const int* __restrict__ ei, const float* __restrict__ x,
            const float* __restrict__ WE, const float* __restrict__ W_up,
            const float* __restrict__ Wm1, const float* __restrict__ Wm2,
            const float* __restrict__ Wm3, const float* __restrict__ W_out,
            const float* __restrict__ W_sc, const float* __restrict__ a_sc,
            const float* __restrict__ w_poly, const float* __restrict__ W_prod,
            const float* __restrict__ w_r0, const float* __restrict__ W_r1,
            const float* __restrict__ w_r2, const int* __restrict__ batch,
            int* __restrict__ spec, float* __restrict__ u3c,
            float* __restrict__ frc, float* __restrict__ dfrc,
            int* __restrict__ esrc, int* __restrict__ edst, int* __restrict__ ecount,
            float* __restrict__ T0, float* __restrict__ SC0, float* __restrict__ W3z,
            float* __restrict__ agg0, float* __restrict__ agg1, float* __restrict__ ghb,
            float* __restrict__ t2b0, float* __restrict__ t2b1, float* __restrict__ w0b1,
            float* __restrict__ h1b, float* __restrict__ nf1b, float* __restrict__ s0b,
            float* __restrict__ gagg0, float* __restrict__ gagg1, float* __restrict__ gacc,
            int* __restrict__ barcnt, float4* __restrict__ zws,
            float* __restrict__ out)
{
    __shared__ float part[8];
    const int bid  = blockIdx.x;
    const int tid  = threadIdx.x;
    const int lane = tid & 63;
    const int gw   = bid*4 + (tid>>6);          // global wave 0..2047 (uniform per wave)

    const float* U0  = W_up;          const float* U1  = W_up   + 16384;
    const float* O0  = W_out;         const float* O1  = W_out  + 16384;
    const float* S0w = W_sc;          const float* S1w = W_sc   + 16384;
    const float* P0w = W_prod;        const float* P1w = W_prod + 16384;
    const float* M1_0= Wm1;           const float* M1_1= Wm1 + 512;
    const float* M2_0= Wm2;           const float* M2_1= Wm2 + 4096;
    const float* asc1= a_sc + ZZ*64;
    const float* pl0 = w_poly;        const float* pl1 = w_poly + 192;
    const float* W3z0= W3z;           const float* W3z1= W3z + 4096;
    float* outf = out + 8 + NN;

    // ================= P1: geometry+compaction / spec / W3z / tables / zero =================
    if (bid < RB_SPEC){
        int e = bid*256 + tid;
        if (e < EE){
            int s = ei[e], r = ei[EE+e];
            float vx = pos[r*3+0]-pos[s*3+0]+shifts[e*3+0];
            float vy = pos[r*3+1]-pos[s*3+1]+shifts[e*3+1];
            float vz = pos[r*3+2]-pos[s*3+2]+shifts[e*3+2];
            float rr = sqrtf(vx*vx+vy*vy+vz*vz);
            float u = rr*(1.0f/RMAX);
            if (u < 1.0f){
                int slot = atomicAdd(ecount, 1);
                esrc[slot]=s; edst[slot]=r;
                float inv = 1.0f/rr;
                u3c[slot*3+0]=vx*inv; u3c[slot*3+1]=vy*inv; u3c[slot*3+2]=vz*inv;
                float u2=u*u, u4=u2*u2, u5=u4*u;
                float env  = 1.0f - 21.0f*u5 + 35.0f*u5*u - 15.0f*u5*u2;
                float om   = 1.0f-u;
                float denv = -21.0f*u4*om*om;
                const float A  = 0.6324555320336759f;    // sqrt(2/RMAX)
                const float K1 = 3.14159265358979f/RMAX;
                float a  = K1*rr;
                float s1 = __sinf(a), c1 = __cosf(a);
                float sp = 0.0f, cp = 1.0f, sn = s1, cn = c1;
#pragma unroll
                for (int n=1;n<=8;n++){
                    float k = (float)n*K1;
                    float bess  = A*sn*inv;
                    float dbess = A*(k*cn - sn*inv)*inv;
                    frc [slot*8+n-1] = bess*env;
                    dfrc[slot*8+n-1] = dbess*env + bess*denv;
                    float s2 = 2.0f*c1*sn - sp; sp=sn; sn=s2;
                    float c2 = 2.0f*c1*cn - cp; cp=cn; cn=c2;
                }
            }
        }
    } else if (bid < RB_W3Z){
        int n = (bid-RB_SPEC)*256 + tid;
        if (n < NN){
            int sp = 0;
#pragma unroll
            for (int j=0;j<ZZ;j++) if (x[n*ZZ+j] > 0.5f) sp = j;
            spec[n] = sp;
        }
    } else if (bid < RB_T0){
        int idx = (bid-RB_W3Z)*256 + tid;      // 0..8191
        int l = idx >> 12, kc = idx & 4095;
        int k = kc >> 6, c = kc & 63;
        W3z[idx] = Wm3[l*64*256 + k*256 + 4*c];
    } else if (bid < RB_ZERO){
        int wv = (bid-RB_T0)*4 + (tid>>6);
        if (wv < ZZ){
            float wev = WE[wv*64 + lane];
            float t=0.f, sc=0.f;
#pragma unroll
            for (int c=0;c<64;c++){
                float w = rl(wev,c);
                t  += w*U0 [c*64+lane];
                sc += w*S0w[c*64+lane];
            }
            T0 [wv*64+lane] = t;
            SC0[wv*64+lane] = sc * a_sc[wv*64+lane];
        }
    } else {
        float4 z4 = make_float4(0.f,0.f,0.f,0.f);
        float4* zout = (float4*)outf;
        for (int i=(bid-RB_ZERO)*256 + tid; i < ZWS_F4 + ZOUT_F4; i += (GRID-RB_ZERO)*256){
            if (i < ZWS_F4) zws[i] = z4;
            else zout[i-ZWS_F4] = z4;
        }
    }
    gbar(barcnt, 0);

    // ================= P2: edge MLP fwd layer0 (stash t2b0) =================
    {
        float W1c[8], W2c[64], W3c[64];
#pragma unroll
        for (int j=0;j<8;j++) W1c[j] = M1_0[j*64+lane];
        load_col64(M2_0, lane, W2c);
        load_col64(W3z0, lane, W3c);
        pin8(W1c); pin64(W2c); pin64(W3c);
        int cnt = ecount[0];
        for (int slot=gw; slot<cnt; slot+=NWAVE){
            int s = esrc[slot], r = edst[slot];
            float fv = frc[slot*8 + (lane&7)];
            float t1=0.f;
#pragma unroll
            for (int j=0;j<8;j++) t1 += rl(fv,j)*W1c[j];
            float t2 = bmv64(siluf(t1), W2c);
            t2b0[(size_t)slot*64+lane] = t2;
            float w0 = bmv64(siluf(t2), W3c);
            float h  = T0[spec[s]*64+lane];
            atomicAdd(&agg0[r*64+lane], w0*h*INV_AVG);
        }
    }
    gbar(barcnt, 1);

    // ================= P3: node fwd layer0 (s0, nf1, h1, node_e, snap) =================
    {
        if (tid < 8) part[tid] = 0.f;
        __syncthreads();
        float WA[64], WB[64], WC[64];
        load_col64(O0,  lane, WA);
        load_col64(P0w, lane, WB);
        load_col64(U1,  lane, WC);
        pin64(WA); pin64(WB); pin64(WC);
        float p0=pl0[lane], p1=pl0[64+lane], p2=pl0[128+lane];
        float w0r = w_r0[lane];
        for (int n=gw; n<NN; n+=NWAVE){
            float av = agg0[n*64+lane];
            float s  = bmv64(av, WA);
            float gate = p0 + p1*s + p2*s*s;
            float nf = bmv64(s*gate, WB) + SC0[spec[n]*64+lane];
            s0b [n*64+lane] = s;
            nf1b[n*64+lane] = nf;
            h1b [n*64+lane] = bmv64(nf, WC);
            float ne = nf*w0r;
#pragma unroll
            for (int off=32;off;off>>=1) ne += __shfl_xor(ne,off);
            if (lane==0){ out[8+n] = ne; atomicAdd(&part[batch[n]], ne); }
        }
        __syncthreads();
        if (tid < 8) atomicAdd(&out[tid], part[tid]);
    }
    gbar(barcnt, 2);

    // ================= P4: edge MLP fwd layer1 (stash t2b1, w0b1) =================
    {
        float W1c[8], W2c[64], W3c[64];
#pragma unroll
        for (int j=0;j<8;j++) W1c[j] = M1_1[j*64+lane];
        load_col64(M2_1, lane, W2c);
        load_col64(W3z1, lane, W3c);
        pin8(W1c); pin64(W2c); pin64(W3c);
        int cnt = ecount[0];
        for (int slot=gw; slot<cnt; slot+=NWAVE){
            int s = esrc[slot], r = edst[slot];
            float fv = frc[slot*8 + (lane&7)];
            float t1=0.f;
#pragma unroll
            for (int j=0;j<8;j++) t1 += rl(fv,j)*W1c[j];
            float t2 = bmv64(siluf(t1), W2c);
            t2b1[(size_t)slot*64+lane] = t2;
            float w0 = bmv64(siluf(t2), W3c);
            w0b1[(size_t)slot*64+lane] = w0;
            float h  = h1b[s*64+lane];
            atomicAdd(&agg1[r*64+lane], w0*h*INV_AVG);
        }
    }
    gbar(barcnt, 3);

    // ================= P5: fused node layer1 fwd + readout fwd/bwd + node bwd =================
    {
        if (tid < 8) part[tid] = 0.f;
        __syncthreads();
        float WA[64], WB[64], WC[64];
        float p0=pl1[lane], p1=pl1[64+lane], p2=pl1[128+lane];
        int na = gw, nb = gw + NWAVE;
        bool vb = nb < NN;                      // na always < NN (2048 <= 4000)
        int spa = spec[na], spb = vb ? spec[nb] : 0;
        float sA, sB=0.f, nfA, nfB=0.f, gA, gB=0.f;
        // phase a: forward (col-form)
        load_col64(O1,  lane, WA);
        load_col64(P1w, lane, WB);
        load_col64(S1w, lane, WC);
        pin64(WA); pin64(WB); pin64(WC);
        {
            float av  = agg1[na*64+lane];
            float nfv = nf1b[na*64+lane];
            sA = bmv64(av, WA);
            float gate = p0 + p1*sA + p2*sA*sA;
            nfA = bmv64(sA*gate, WB) + bmv64(nfv, WC)*asc1[spa*64+lane];
        }
        if (vb){
            float av  = agg1[nb*64+lane];
            float nfv = nf1b[nb*64+lane];
            sB = bmv64(av, WA);
            float gate = p0 + p1*sB + p2*sB*sB;
            nfB = bmv64(sB*gate, WB) + bmv64(nfv, WC)*asc1[spb*64+lane];
        }
        // phase b: readout fwd + bwd
        {
            int j = lane & 15;
            float w2 = w_r2[j];
#pragma unroll
            for (int c=0;c<64;c++) WA[c] = W_r1[c*16 + j];
            pin64(WA);
            float WR[16];
#pragma unroll
            for (int i2=0;i2<4;i2++){
                float4 v = reinterpret_cast<const float4*>(W_r1 + lane*16)[i2];
                WR[4*i2]=v.x; WR[4*i2+1]=v.y; WR[4*i2+2]=v.z; WR[4*i2+3]=v.w;
            }
            {
                float z  = bmv64(nfA, WA);
                float ne = siluf(z)*w2;
#pragma unroll
                for (int off=32;off;off>>=1) ne += __shfl_xor(ne,off);
                ne *= 0.25f;
                float gz = w2*dsiluf(z);
                float g = 0.f;
#pragma unroll
                for (int jj=0;jj<16;jj++) g += rl(gz,jj)*WR[jj];
                gA = g;
                if (lane==0){ out[8+na] += ne; atomicAdd(&part[batch[na]], ne); }
            }
            if (vb){
                float z  = bmv64(nfB, WA);
                float ne = siluf(z)*w2;
#pragma unroll
                for (int off=32;off;off>>=1) ne += __shfl_xor(ne,off);
                ne *= 0.25f;
                float gz = w2*dsiluf(z);
                float g = 0.f;
#pragma unroll
                for (int jj=0;jj<16;jj++) g += rl(gz,jj)*WR[jj];
                gB = g;
                if (lane==0){ out[8+nb] += ne; atomicAdd(&part[batch[nb]], ne); }
            }
        }
        // phase c: node bwd (row-form)
        load_row64(P1w + lane*64, WA);
        load_row64(O1  + lane*64, WB);
        load_row64(S1w + lane*64, WC);
        pin64(WA); pin64(WB); pin64(WC);
        {
            float gv = bmv64(gA, WA);
            float gate = p0 + p1*sA + p2*sA*sA;
            float gs = gv*(gate + sA*(p1 + 2.0f*p2*sA));
            gagg1[na*64+lane] = bmv64(gs, WB);
            gacc [na*64+lane] = bmv64(gA*asc1[spa*64+lane], WC);
        }
        if (vb){
            float gv = bmv64(gB, WA);
            float gate = p0 + p1*sB + p2*sB*sB;
            float gs = gv*(gate + sB*(p1 + 2.0f*p2*sB));
            gagg1[nb*64+lane] = bmv64(gs, WB);
            gacc [nb*64+lane] = bmv64(gB*asc1[spb*64+lane], WC);
        }
        __syncthreads();
        if (tid < 8) atomicAdd(&out[tid], part[tid]);
    }
    gbar(barcnt, 4);

    // ================= P6: edge bwd layer1 (ghb + forces) =================
    {
        float W3r[64], W2r[64], W1c[8];
        load_row64(W3z1 + lane*64, W3r);
        load_row64(M2_1 + lane*64, W2r);
#pragma unroll
        for (int j=0;j<8;j++) W1c[j] = M1_1[j*64+lane];
        pin64(W3r); pin64(W2r); pin8(W1c);
        int cnt = ecount[0];
        for (int slot=gw; slot<cnt; slot+=NWAVE){
            int s = esrc[slot], r = edst[slot];
            float gm = gagg1[r*64+lane]*INV_AVG;
            float h  = h1b[s*64+lane];
            atomicAdd(&ghb[s*64+lane], gm*w0b1[(size_t)slot*64+lane]);
            float ga2 = bmv64(gm*h, W3r);
            float gt2 = ga2*dsiluf(t2b1[(size_t)slot*64+lane]);
            float ga1 = bmv64(gt2, W2r);
            float fv  = frc [slot*8+(lane&7)];
            float dfv = dfrc[slot*8+(lane&7)];
            float t1=0.f, wd=0.f;
#pragma unroll
            for (int j=0;j<8;j++){ t1 += rl(fv,j)*W1c[j]; wd += rl(dfv,j)*W1c[j]; }
            float p = ga1*dsiluf(t1)*wd;
#pragma unroll
            for (int off=32;off;off>>=1) p += __shfl_xor(p,off);
            if (lane<3) atomicAdd(&outf[r*3+lane], -u3c[slot*3+lane]*p);
            else if (lane>=32 && lane<35){ int d=lane-32; atomicAdd(&outf[s*3+d], u3c[slot*3+d]*p); }
        }
    }
    gbar(barcnt, 5);

    // ================= P7: assemble gnf1 + node bwd layer0 -> gagg0 =================
    {
        float WA[64], WB[64], WC[64];
        load_row64(U1  + lane*64, WA);
        load_row64(P0w + lane*64, WB);
        load_row64(O0  + lane*64, WC);
        pin64(WA); pin64(WB); pin64(WC);
        float p0=pl0[lane], p1=pl0[64+lane], p2=pl0[128+lane];
        float w0r = w_r0[lane];
        for (int n=gw; n<NN; n+=NWAVE){
            float g  = bmv64(ghb[n*64+lane], WA) + gacc[n*64+lane] + w0r;
            float gv = bmv64(g, WB);
            float s  = s0b[n*64+lane];
            float gate = p0 + p1*s + p2*s*s;
            float gs = gv*(gate + s*(p1 + 2.0f*p2*s));
            gagg0[n*64+lane] = bmv64(gs, WC);
        }
    }
    gbar(barcnt, 6);

    // ================= P8: edge bwd layer0 (forces; uses t2b0 stash) =================
    {
        float W3r[64], W2r[64], W1c[8];
        load_row64(W3z0 + lane*64, W3r);
        load_row64(M2_0 + lane*64, W2r);
#pragma unroll
        for (int j=0;j<8;j++) W1c[j] = M1_0[j*64+lane];
        pin64(W3r); pin64(W2r); pin8(W1c);
        int cnt = ecount[0];
        for (int slot=gw; slot<cnt; slot+=NWAVE){
            int s = esrc[slot], r = edst[slot];
            float gm = gagg0[r*64+lane]*INV_AVG;
            float h  = T0[spec[s]*64+lane];
            float ga2 = bmv64(gm*h, W3r);
            float gt2 = ga2*dsiluf(t2b0[(size_t)slot*64+lane]);
            float ga1 = bmv64(gt2, W2r);
            float fv  = frc [slot*8+(lane&7)];
            float dfv = dfrc[slot*8+(lane&7)];
            float t1=0.f, wd=0.f;
#pragma unroll
            for (int j=0;j<8;j++){ t1 += rl(fv,j)*W1c[j]; wd += rl(dfv,j)*W1c[j]; }
            float p = ga1*dsiluf(t1)*wd;
#pragma unroll
            for (int off=32;off;off>>=1) p += __shfl_xor(p,off);
            if (lane<3) atomicAdd(&outf[r*3+lane], -u3c[slot*3+lane]*p);
            else if (lane>=32 && lane<35){ int d=lane-32; atomicAdd(&outf[s*3+d], u3c[slot*3+d]*p); }
        }
    }
}

extern "C" void kernel_launch(void* const* d_in, const int* in_sizes, int n_in,
                              void* d_out, int out_size, void* d_ws, size_t ws_size,
                              hipStream_t stream)
{
    (void)in_sizes; (void)n_in; (void)out_size; (void)ws_size;
    const float* pos    = (const float*)d_in[0];
    const float* x      = (const float*)d_in[1];
    const float* shifts = (const float*)d_in[2];
    const float* W_embed= (const float*)d_in[3];
    const float* W_up   = (const float*)d_in[4];
    const float* Wm1    = (const float*)d_in[5];
    const float* Wm2    = (const float*)d_in[6];
    const float* Wm3    = (const float*)d_in[7];
    const float* W_out  = (const float*)d_in[8];
    const float* W_sc   = (const float*)d_in[9];
    const float* a_sc   = (const float*)d_in[10];
    const float* w_poly = (const float*)d_in[11];
    const float* W_prod = (const float*)d_in[12];
    const float* w_r0   = (const float*)d_in[13];
    const float* W_r1   = (const float*)d_in[14];
    const float* w_r2   = (const float*)d_in[15];
    const int*   ei     = (const int*)d_in[16];
    const int*   batch  = (const int*)d_in[17];
    float* out = (float*)d_out;

    float* F = (float*)d_ws;
    float* agg0 = F; F += NN*64;          // ← zws zero region starts here
    float* agg1 = F; F += NN*64;
    float* ghb  = F; F += NN*64;
    float* u3c  = F; F += 3*EE;
    float* frc  = F; F += 8*EE;
    float* dfrc = F; F += 8*EE;
    float* t2b0 = F; F += (size_t)EE*64;
    float* t2b1 = F; F += (size_t)EE*64;
    float* w0b1 = F; F += (size_t)EE*64;
    float* h1b  = F; F += NN*64;
    float* nf1b = F; F += NN*64;
    float* s0b  = F; F += NN*64;
    float* gagg1= F; F += NN*64;
    float* gagg0= F; F += NN*64;
    float* gacc = F; F += NN*64;
    float* T0   = F; F += ZZ*64;
    float* SC0  = F; F += ZZ*64;
    float* W3z  = F; F += 2*64*64;
    int* spec   = (int*)F; F += NN;
    int* esrc   = (int*)F; F += EE;
    int* edst   = (int*)F; F += EE;
    int* ecount = (int*)F; F += 4;
    int* barcnt = (int*)F; F += 512;      // 7 barriers x 64-int stride

    k_zero<<<1, 256, 0, stream>>>(barcnt, ecount, out);
    k_main<<<GRID, 256, 0, stream>>>(pos, shifts, ei, x, W_embed, W_up, Wm1, Wm2, Wm3,
                                     W_out, W_sc, a_sc, w_poly, W_prod, w_r0, W_r1, w_r2,
                                     batch, spec, u3c, frc, dfrc, esrc, edst, ecount,
                                     T0, SC0, W3z, agg0, agg1, ghb, t2b0, t2b1, w0b1,
                                     h1b, nf1b, s0b, gagg0, gagg1, gacc,
                                     barcnt, (float4*)d_ws, out);
}

// Round 7
// 157.919 us; speedup vs baseline: 4.0219x; 4.0219x over previous
//
#include <hip/hip_runtime.h>
#include <math.h>

constexpr int NN = 4000;
constexpr int EE = 48000;
constexpr int ZZ = 10;
constexpr float RMAX = 5.0f;
constexpr float INV_AVG = 1.0f / 12.0f;

// geom role-block layout
constexpr int GB_EDGE = 188;          // [0,188)   edges
constexpr int GB_SPEC = GB_EDGE + 16; // [188,204) species
constexpr int GB_W3Z  = GB_SPEC + 32; // [204,236) Wm3 l=0 gather
constexpr int GB_T0   = GB_W3Z + 3;   // [236,239) per-species tables
constexpr int GB_ZERO = GB_T0 + 64;   // [239,303) zero agg0/agg1/ghb + out force region
constexpr int ZWS_F4  = 3*NN*64/4;    // agg0,agg1,ghb at ws base
constexpr int ZOUT_F4 = 3*NN/4;       // out force region

__device__ __forceinline__ float rl(float v, int lane){
    return __uint_as_float(__builtin_amdgcn_readlane(__float_as_uint(v), lane));
}
__device__ __forceinline__ float sigf(float x){ return 1.0f/(1.0f+__expf(-x)); }
__device__ __forceinline__ float siluf(float x){ return x*sigf(x); }
__device__ __forceinline__ float dsiluf(float x){ float s=sigf(x); return s*(1.0f+x*(1.0f-s)); }

__device__ __forceinline__ void pin64(float (&W)[64]){
#pragma unroll
    for (int i=0;i<64;i++) asm volatile("" : "+v"(W[i]));
}
__device__ __forceinline__ void pin8(float (&W)[8]){
#pragma unroll
    for (int i=0;i<8;i++) asm volatile("" : "+v"(W[i]));
}

__device__ __forceinline__ float bmv64(float src, const float (&W)[64]){
    float a0=0.f,a1=0.f,a2=0.f,a3=0.f;
#pragma unroll
    for (int k=0;k<64;k+=4){
        a0 += rl(src,k+0)*W[k+0];
        a1 += rl(src,k+1)*W[k+1];
        a2 += rl(src,k+2)*W[k+2];
        a3 += rl(src,k+3)*W[k+3];
    }
    return (a0+a1)+(a2+a3);
}
__device__ __forceinline__ void load_row64(const float* __restrict__ p, float (&W)[64]){
#pragma unroll
    for (int i=0;i<16;i++){
        float4 v = reinterpret_cast<const float4*>(p)[i];
        W[4*i]=v.x; W[4*i+1]=v.y; W[4*i+2]=v.z; W[4*i+3]=v.w;
    }
}
__device__ __forceinline__ void load_col64(const float* __restrict__ p, int lane, float (&W)[64]){
#pragma unroll
    for (int k=0;k<64;k++) W[k] = p[k*64+lane];
}

// ---------------- tiny zero: ecount + snap header ----------------
__global__ void k_zero(int* __restrict__ ecount, float* __restrict__ out)
{
    int t = threadIdx.x;
    if (t < 8) out[t] = 0.0f;
    if (t == 8) *ecount = 0;
}

// ---------------- geometry/compaction + spec + precompute + big zero (role blocks) ----------------
__global__ void k_geom(const float* __restrict__ pos, const float* __restrict__ shifts,
                       const int* __restrict__ ei, const float* __restrict__ x,
                       const float* __restrict__ WE, const float* __restrict__ W_up,
                       const float* __restrict__ W_sc, const float* __restrict__ a_sc,
                       const float* __restrict__ Wm3,
                       int* __restrict__ spec,
                       float* __restrict__ u3c, float* __restrict__ frc, float* __restrict__ dfrc,
                       int* __restrict__ esrc, int* __restrict__ edst, int* __restrict__ ecount,
                       float* __restrict__ T0, float* __restrict__ SC0, float* __restrict__ W3z,
                       float4* __restrict__ zws, float* __restrict__ out)
{
    int b = blockIdx.x;
    if (b >= GB_ZERO) return;
    if (b >= GB_T0){                     // zero role: agg0/agg1/ghb + out force region
        float4 z4 = make_float4(0.f,0.f,0.f,0.f);
        float4* zout = (float4*)(out + 8 + NN);
        for (int i=(b-GB_T0)*256 + threadIdx.x; i < ZWS_F4 + ZOUT_F4; i += 64*256){
            if (i < ZWS_F4) zws[i] = z4;
            else zout[i-ZWS_F4] = z4;
        }
        return;
    }
    if (b >= GB_W3Z){                    // T0/SC0 per-species tables
        int wv = (b-GB_W3Z)*4 + (threadIdx.x>>6);
        int lane = threadIdx.x & 63;
        if (wv < ZZ){
            float wev = WE[wv*64 + lane];
            float t=0.f, sc=0.f;
#pragma unroll
            for (int c=0;c<64;c++){
                float w = rl(wev,c);
                t  += w*W_up[c*64+lane];
                sc += w*W_sc[c*64+lane];
            }
            T0[wv*64+lane]  = t;
            SC0[wv*64+lane] = sc * a_sc[wv*64+lane];
        }
        return;
    }
    if (b >= GB_SPEC){                   // W3z gather: Wm3 l=0 slice -> dense 2x64x64
        int idx = (b-GB_SPEC)*256 + threadIdx.x;
        int l = idx >> 12;
        int kc = idx & 4095;
        int k = kc >> 6, c = kc & 63;
        W3z[idx] = Wm3[l*64*256 + k*256 + 4*c];
        return;
    }
    if (b >= GB_EDGE){                   // species from one-hot
        int n = (b-GB_EDGE)*256 + threadIdx.x;
        if (n < NN){
            int sp = 0;
#pragma unroll
            for (int j=0;j<ZZ;j++) if (x[n*ZZ+j] > 0.5f) sp = j;
            spec[n] = sp;
        }
        return;
    }
    int e = b*256 + threadIdx.x;         // edges: geometry + radial + compaction
    if (e >= EE) return;
    int s = ei[e], r = ei[EE+e];
    float vx = pos[r*3+0]-pos[s*3+0]+shifts[e*3+0];
    float vy = pos[r*3+1]-pos[s*3+1]+shifts[e*3+1];
    float vz = pos[r*3+2]-pos[s*3+2]+shifts[e*3+2];
    float rr = sqrtf(vx*vx+vy*vy+vz*vz);
    float u = rr*(1.0f/RMAX);
    if (u >= 1.0f) return;               // env=0 -> zero message and zero force
    int slot = atomicAdd(ecount, 1);
    esrc[slot]=s; edst[slot]=r;
    float inv = 1.0f/rr;
    u3c[slot*3+0]=vx*inv; u3c[slot*3+1]=vy*inv; u3c[slot*3+2]=vz*inv;
    float u2=u*u, u4=u2*u2, u5=u4*u;
    float env  = 1.0f - 21.0f*u5 + 35.0f*u5*u - 15.0f*u5*u2;
    float om   = 1.0f-u;
    float denv = -21.0f*u4*om*om;
    const float A = 0.6324555320336759f;    // sqrt(2/RMAX)
    const float K1 = 3.14159265358979f/RMAX;
    float a  = K1*rr;
    float s1 = __sinf(a), c1 = __cosf(a);
    float sp = 0.0f, cp = 1.0f, sn = s1, cn = c1;
#pragma unroll
    for (int n=1;n<=8;n++){
        float k = (float)n*K1;
        float bess  = A*sn*inv;
        float dbess = A*(k*cn - sn*inv)*inv;
        frc [slot*8+n-1] = bess*env;
        dfrc[slot*8+n-1] = dbess*env + bess*denv;
        float s2 = 2.0f*c1*sn - sp; sp=sn; sn=s2;
        float c2 = 2.0f*c1*cn - cp; cp=cn; cn=c2;
    }
}

// ---------------- fused edge MLP forward (stash t2; L=1 also w0) ----------------
template<int L>
__global__ __launch_bounds__(256,3)
void k_edge_fwd(const float* __restrict__ frc, const int* __restrict__ esrc,
                const int* __restrict__ edst, const int* __restrict__ ecount,
                const int* __restrict__ spec, const float* __restrict__ T0,
                const float* __restrict__ h1,
                const float* __restrict__ W1, const float* __restrict__ W2,
                const float* __restrict__ W3z,
                float* __restrict__ agg, float* __restrict__ t2b,
                float* __restrict__ w0b)
{
    int lane = threadIdx.x & 63;
    int wid  = (blockIdx.x*256 + threadIdx.x) >> 6;
    int nw   = gridDim.x*4;
    int cnt  = ecount[0];
    float W1c[8], W2c[64], W3c[64];
#pragma unroll
    for (int j=0;j<8;j++) W1c[j] = W1[j*64+lane];
    load_col64(W2,  lane, W2c);
    load_col64(W3z, lane, W3c);
    pin8(W1c); pin64(W2c); pin64(W3c);
    for (int slot=wid; slot<cnt; slot+=nw){
        int us = __builtin_amdgcn_readfirstlane(slot);
        int s = esrc[us], r = edst[us];
        float fv = frc[us*8 + (lane&7)];
        float t1=0.f;
#pragma unroll
        for (int j=0;j<8;j++) t1 += rl(fv,j)*W1c[j];
        float a1v = siluf(t1);
        float t2  = bmv64(a1v, W2c);
        t2b[(size_t)us*64+lane] = t2;
        float a2v = siluf(t2);
        float w0  = bmv64(a2v, W3c);
        if (L==1) w0b[(size_t)us*64+lane] = w0;
        float h = (L==0) ? T0[spec[s]*64+lane] : h1[s*64+lane];
        atomicAdd(&agg[r*64+lane], w0*h*INV_AVG);
    }
}

// ---------------- node fwd layer0: s0, nf1, h1, node_e -> out, snap partial ----------------
__global__ __launch_bounds__(256,2)
void k_node_fwd0(const float* __restrict__ agg, const float* __restrict__ SC0,
                 const int* __restrict__ spec, const int* __restrict__ batch,
                 const float* __restrict__ Wout, const float* __restrict__ Wprod,
                 const float* __restrict__ Wup1, const float* __restrict__ poly,
                 const float* __restrict__ wr0,
                 float* __restrict__ s0, float* __restrict__ nf1,
                 float* __restrict__ h1, float* __restrict__ out)
{
    __shared__ float part[8];
    if (threadIdx.x < 8) part[threadIdx.x] = 0.f;
    __syncthreads();
    int lane = threadIdx.x & 63;
    int wid = (blockIdx.x*256 + threadIdx.x) >> 6;
    int nw  = gridDim.x*4;
    float WA[64], WB[64], WC[64];
    load_col64(Wout, lane, WA);
    load_col64(Wprod,lane, WB);
    load_col64(Wup1, lane, WC);
    pin64(WA); pin64(WB); pin64(WC);
    float p0=poly[lane], p1=poly[64+lane], p2=poly[128+lane];
    float w0r = wr0[lane];
    for (int nn=wid; nn<NN; nn+=nw){
        int n = __builtin_amdgcn_readfirstlane(nn);
        float av = agg[n*64+lane];
        float s  = bmv64(av, WA);
        float gate = p0 + p1*s + p2*s*s;
        float nf = bmv64(s*gate, WB) + SC0[spec[n]*64+lane];
        s0 [n*64+lane] = s;
        nf1[n*64+lane] = nf;
        h1 [n*64+lane] = bmv64(nf, WC);
        float ne = nf*w0r;
#pragma unroll
        for (int off=32;off;off>>=1) ne += __shfl_xor(ne,off);
        if (lane==0){ out[8+n] = ne; atomicAdd(&part[batch[n]], ne); }
    }
    __syncthreads();
    if (threadIdx.x < 8) atomicAdd(&out[threadIdx.x], part[threadIdx.x]);
}

// ---------------- node update fwd, layer1 ----------------
__global__ __launch_bounds__(256,2)
void k_node_fwd1(const float* __restrict__ agg, const float* __restrict__ nf1,
                 const int* __restrict__ spec, const float* __restrict__ Wout,
                 const float* __restrict__ Wprod, const float* __restrict__ Wsc,
                 const float* __restrict__ asc, const float* __restrict__ poly,
                 float* __restrict__ s1, float* __restrict__ nf2)
{
    int lane = threadIdx.x & 63;
    int wid = (blockIdx.x*256 + threadIdx.x) >> 6;
    int nw  = gridDim.x*4;
    float Oc[64], Pc[64], Sc[64];
    load_col64(Wout, lane, Oc);
    load_col64(Wprod,lane, Pc);
    load_col64(Wsc,  lane, Sc);
    pin64(Oc); pin64(Pc); pin64(Sc);
    float p0=poly[lane], p1=poly[64+lane], p2=poly[128+lane];
    for (int nn=wid; nn<NN; nn+=nw){
        int n = __builtin_amdgcn_readfirstlane(nn);
        float av  = agg[n*64+lane];
        float nfv = nf1[n*64+lane];
        float s   = bmv64(av, Oc);
        float gate = p0 + p1*s + p2*s*s;
        float v   = s*gate;
        float scp = bmv64(nfv, Sc);
        float nf  = bmv64(v, Pc) + scp*asc[spec[n]*64+lane];
        s1 [n*64+lane] = s;
        nf2[n*64+lane] = nf;
    }
}

// ---------------- readout layer1: node_e -> out (+snap), gnf2 ----------------
__global__ __launch_bounds__(256,3)
void k_read1(const float* __restrict__ nf2, const int* __restrict__ batch,
             const float* __restrict__ Wr1, const float* __restrict__ wr2,
             float* __restrict__ out, float* __restrict__ gnf2)
{
    __shared__ float part[8];
    if (threadIdx.x < 8) part[threadIdx.x] = 0.f;
    __syncthreads();
    int lane = threadIdx.x & 63;
    int wid = (blockIdx.x*256 + threadIdx.x) >> 6;
    int nw  = gridDim.x*4;
    int j = lane & 15;
    float Wcol[64];
#pragma unroll
    for (int c=0;c<64;c++) Wcol[c] = Wr1[c*16 + j];
    pin64(Wcol);
    float Wrow[16];
#pragma unroll
    for (int i=0;i<4;i++){
        float4 v = reinterpret_cast<const float4*>(Wr1 + lane*16)[i];
        Wrow[4*i]=v.x; Wrow[4*i+1]=v.y; Wrow[4*i+2]=v.z; Wrow[4*i+3]=v.w;
    }
    float w2 = wr2[j];
    for (int nn=wid; nn<NN; nn+=nw){
        int n = __builtin_amdgcn_readfirstlane(nn);
        float nv = nf2[n*64+lane];
        float z  = bmv64(nv, Wcol);        // z_{lane&15}, replicated 4x
        float ne = siluf(z)*w2;
#pragma unroll
        for (int off=32;off;off>>=1) ne += __shfl_xor(ne,off);
        ne *= 0.25f;
        float gz = w2*dsiluf(z);
        float g = 0.f;
#pragma unroll
        for (int jj=0;jj<16;jj++) g += rl(gz,jj)*Wrow[jj];
        gnf2[n*64+lane] = g;
        if (lane==0){ out[8+n] += ne; atomicAdd(&part[batch[n]], ne); }
    }
    __syncthreads();
    if (threadIdx.x < 8) atomicAdd(&out[threadIdx.x], part[threadIdx.x]);
}

// ---------------- backward node layer1: gnf2 -> gagg1, gacc(sc path) ----------------
__global__ __launch_bounds__(256,2)
void k_bnode1(const float* __restrict__ gin, const float* __restrict__ sbuf,
              const float* __restrict__ Wout, const float* __restrict__ Wprod,
              const float* __restrict__ Wsc, const float* __restrict__ asc,
              const int* __restrict__ spec, const float* __restrict__ poly,
              float* __restrict__ gagg, float* __restrict__ gsc)
{
    int lane = threadIdx.x & 63;
    int wid = (blockIdx.x*256 + threadIdx.x) >> 6;
    int nw  = gridDim.x*4;
    float Pr[64], Or[64], Sr[64];
    load_row64(Wprod + lane*64, Pr);
    load_row64(Wout  + lane*64, Or);
    load_row64(Wsc   + lane*64, Sr);
    pin64(Pr); pin64(Or); pin64(Sr);
    float p0=poly[lane], p1=poly[64+lane], p2=poly[128+lane];
    for (int nn=wid; nn<NN; nn+=nw){
        int n = __builtin_amdgcn_readfirstlane(nn);
        float g  = gin[n*64+lane];
        float gv = bmv64(g, Pr);
        float s  = sbuf[n*64+lane];
        float gate = p0 + p1*s + p2*s*s;
        float gs = gv*(gate + s*(p1 + 2.0f*p2*s));
        gagg[n*64+lane] = bmv64(gs, Or);
        float ga = g * asc[spec[n]*64+lane];
        gsc[n*64+lane] = bmv64(ga, Sr);
    }
}

// ---------------- fused: gnf1 = ghb@U1^T + gacc + wr0 ; then bnode layer0 -> gagg0 ----------------
__global__ __launch_bounds__(256,2)
void k_bnode0(const float* __restrict__ ghb, const float* __restrict__ gacc,
              const float* __restrict__ Wup1, const float* __restrict__ wr0,
              const float* __restrict__ sbuf, const float* __restrict__ Wout,
              const float* __restrict__ Wprod, const float* __restrict__ poly,
              float* __restrict__ gagg)
{
    int lane = threadIdx.x & 63;
    int wid = (blockIdx.x*256 + threadIdx.x) >> 6;
    int nw  = gridDim.x*4;
    float Ur[64], Pr[64], Or[64];
    load_row64(Wup1 + lane*64, Ur);
    load_row64(Wprod+ lane*64, Pr);
    load_row64(Wout + lane*64, Or);
    pin64(Ur); pin64(Pr); pin64(Or);
    float p0=poly[lane], p1=poly[64+lane], p2=poly[128+lane];
    for (int nn=wid; nn<NN; nn+=nw){
        int n = __builtin_amdgcn_readfirstlane(nn);
        float gh = ghb[n*64+lane];
        float g  = bmv64(gh, Ur) + gacc[n*64+lane] + wr0[lane];
        float gv = bmv64(g, Pr);
        float s  = sbuf[n*64+lane];
        float gate = p0 + p1*s + p2*s*s;
        float gs = gv*(gate + s*(p1 + 2.0f*p2*s));
        gagg[n*64+lane] = bmv64(gs, Or);
    }
}

// ---------------- backward edge MLP -> forces into out (+ghb for layer1) ----------------
template<int L>
__global__ __launch_bounds__(256,3)
void k_edge_bwd(const float* __restrict__ frc, const float* __restrict__ dfrc,
                const float* __restrict__ u3c, const int* __restrict__ esrc,
                const int* __restrict__ edst, const int* __restrict__ ecount,
                const int* __restrict__ spec, const float* __restrict__ T0,
                const float* __restrict__ h1, const float* __restrict__ gagg,
                const float* __restrict__ t2b, const float* __restrict__ w0b,
                const float* __restrict__ W1, const float* __restrict__ W2,
                const float* __restrict__ W3z,
                float* __restrict__ ghb, float* __restrict__ out)
{
    int lane = threadIdx.x & 63;
    int wid  = (blockIdx.x*256 + threadIdx.x) >> 6;
    int nw   = gridDim.x*4;
    int cnt  = ecount[0];
    float* outf = out + 8 + NN;
    float W3r[64], W2r[64], W1c[8];
    load_row64(W3z + lane*64, W3r);
    load_row64(W2  + lane*64, W2r);
#pragma unroll
    for (int j=0;j<8;j++) W1c[j] = W1[j*64+lane];
    pin64(W3r); pin64(W2r); pin8(W1c);
    for (int slot=wid; slot<cnt; slot+=nw){
        int us = __builtin_amdgcn_readfirstlane(slot);
        int s = esrc[us], r = edst[us];
        float gm = gagg[r*64+lane]*INV_AVG;
        float h  = (L==0) ? T0[spec[s]*64+lane] : h1[s*64+lane];
        float gw0 = gm*h;
        if (L==1) atomicAdd(&ghb[s*64+lane], gm*w0b[(size_t)us*64+lane]);
        float ga2 = bmv64(gw0, W3r);
        float t2v = t2b[(size_t)us*64+lane];
        float gt2 = ga2*dsiluf(t2v);
        float ga1 = bmv64(gt2, W2r);
        float fv  = frc [us*8+(lane&7)];
        float dfv = dfrc[us*8+(lane&7)];
        float t1=0.f, wd=0.f;
#pragma unroll
        for (int j=0;j<8;j++){ t1 += rl(fv,j)*W1c[j]; wd += rl(dfv,j)*W1c[j]; }
        float gt1 = ga1*dsiluf(t1);
        float p = gt1*wd;
#pragma unroll
        for (int off=32;off;off>>=1) p += __shfl_xor(p,off);
        if (lane<3) atomicAdd(&outf[r*3+lane], -u3c[us*3+lane]*p);
        else if (lane>=32 && lane<35){ int d=lane-32; atomicAdd(&outf[s*3+d], u3c[us*3+d]*p); }
    }
}

extern "C" void kernel_launch(void* const* d_in, const int* in_sizes, int n_in,
                              void* d_out, int out_size, void* d_ws, size_t ws_size,
                              hipStream_t stream)
{
    (void)in_sizes; (void)n_in; (void)out_size; (void)ws_size;
    const float* pos    = (const float*)d_in[0];
    const float* x      = (const float*)d_in[1];
    const float* shifts = (const float*)d_in[2];
    const float* W_embed= (const float*)d_in[3];
    const float* W_up   = (const float*)d_in[4];
    const float* Wm1    = (const float*)d_in[5];
    const float* Wm2    = (const float*)d_in[6];
    const float* Wm3    = (const float*)d_in[7];
    const float* W_out  = (const float*)d_in[8];
    const float* W_sc   = (const float*)d_in[9];
    const float* a_sc   = (const float*)d_in[10];
    const float* w_poly = (const float*)d_in[11];
    const float* W_prod = (const float*)d_in[12];
    const float* w_r0   = (const float*)d_in[13];
    const float* W_r1   = (const float*)d_in[14];
    const float* w_r2   = (const float*)d_in[15];
    const int*   ei     = (const int*)d_in[16];
    const int*   batch  = (const int*)d_in[17];
    float* out = (float*)d_out;

    float* F = (float*)d_ws;
    // ---- zero region (geom zero-role covers agg0..ghb) ----
    float* agg0 = F; F += NN*64;
    float* agg1 = F; F += NN*64;
    float* ghb  = F; F += NN*64;
    int* ecount = (int*)F; F += 4;
    // ---- rest ----
    float* u3c  = F; F += 3*EE;
    float* frc  = F; F += 8*EE;
    float* dfrc = F; F += 8*EE;
    float* t2b0 = F; F += (size_t)EE*64;
    float* t2b1 = F; F += (size_t)EE*64;
    float* w0b1 = F; F += (size_t)EE*64;
    float* h1   = F; F += NN*64;
    float* nf1  = F; F += NN*64;
    float* nf2  = F; F += NN*64;
    float* s0   = F; F += NN*64;
    float* s1   = F; F += NN*64;
    float* gnf2 = F; F += NN*64;
    float* gagg1= F; F += NN*64;
    float* gagg0= F; F += NN*64;
    float* gacc = F; F += NN*64;
    float* T0   = F; F += ZZ*64;
    float* SC0  = F; F += ZZ*64;
    float* W3z  = F; F += 2*64*64;
    int* spec   = (int*)F; F += NN;
    int* esrc   = (int*)F; F += EE;
    int* edst   = (int*)F; F += EE;

    const float* U0 = W_up;           const float* U1 = W_up   + 4*64*64;
    const float* O0 = W_out;          const float* O1 = W_out  + 4*64*64;
    const float* S0w= W_sc;           const float* S1w= W_sc   + 4*64*64;
    const float* P0 = W_prod;         const float* P1 = W_prod + 4*64*64;
    const float* M1_0=Wm1,  *M1_1=Wm1+8*64;
    const float* M2_0=Wm2,  *M2_1=Wm2+64*64;
    const float* asc1=a_sc+ZZ*64;
    const float* pl0=w_poly, *pl1=w_poly+3*64;
    float* W3z0 = W3z; float* W3z1 = W3z + 64*64;

    k_zero<<<1, 256, 0, stream>>>(ecount, out);
    k_geom<<<GB_ZERO, 256, 0, stream>>>(pos, shifts, ei, x, W_embed, U0, S0w, a_sc, Wm3,
                                        spec, u3c, frc, dfrc, esrc, edst, ecount,
                                        T0, SC0, W3z, (float4*)d_ws, out);

    // forward
    k_edge_fwd<0><<<768,256,0,stream>>>(frc, esrc, edst, ecount, spec, T0, nullptr,
                                        M1_0, M2_0, W3z0, agg0, t2b0, nullptr);
    k_node_fwd0<<<500,256,0,stream>>>(agg0, SC0, spec, batch, O0, P0, U1, pl0, w_r0,
                                      s0, nf1, h1, out);
    k_edge_fwd<1><<<768,256,0,stream>>>(frc, esrc, edst, ecount, spec, nullptr, h1,
                                        M1_1, M2_1, W3z1, agg1, t2b1, w0b1);
    k_node_fwd1<<<500,256,0,stream>>>(agg1, nf1, spec, O1, P1, S1w, asc1, pl1, s1, nf2);
    k_read1<<<500,256,0,stream>>>(nf2, batch, W_r1, w_r2, out, gnf2);

    // backward
    k_bnode1<<<500,256,0,stream>>>(gnf2, s1, O1, P1, S1w, asc1, spec, pl1, gagg1, gacc);
    k_edge_bwd<1><<<768,256,0,stream>>>(frc, dfrc, u3c, esrc, edst, ecount, spec, nullptr, h1,
                                        gagg1, t2b1, w0b1, M1_1, M2_1, W3z1, ghb, out);
    k_bnode0<<<500,256,0,stream>>>(ghb, gacc, U1, w_r0, s0, O0, P0, pl0, gagg0);
    k_edge_bwd<0><<<768,256,0,stream>>>(frc, dfrc, u3c, esrc, edst, ecount, spec, T0, nullptr,
                                        gagg0, t2b0, nullptr, M1_0, M2_0, W3z0, nullptr, out);
}